// Round 1
// baseline (792.424 us; speedup 1.0000x reference)
//
#include <hip/hip_runtime.h>
#include <hip/hip_bf16.h>
#include <stdint.h>

#define HIDDEN 1024
#define NEXP 16
#define DFF_E 512
#define DFF_S 2048
#define TOKENS 4096
#define NSLOTS 8192  // TOKENS * TOP_K

typedef __bf16 bf16x8 __attribute__((ext_vector_type(8)));
typedef float f32x4 __attribute__((ext_vector_type(4)));

__device__ __forceinline__ unsigned short f2bf(float f) {
  unsigned int u = __builtin_bit_cast(unsigned int, f);
  u += 0x7FFFu + ((u >> 16) & 1u);
  return (unsigned short)(u >> 16);
}
__device__ __forceinline__ float bf2f(unsigned short h) {
  unsigned int u = ((unsigned int)h) << 16;
  return __builtin_bit_cast(float, u);
}
__device__ __forceinline__ void gload16(const void* g, void* l) {
  __builtin_amdgcn_global_load_lds(
      (const __attribute__((address_space(1))) unsigned int*)g,
      (__attribute__((address_space(3))) unsigned int*)l, 16, 0, 0);
}

// ---------------- router: fp32 logits -> softmax -> top2 ----------------
__global__ void router_kernel(const float* __restrict__ x, const float* __restrict__ rw,
                              int* __restrict__ topk_idx, float* __restrict__ topk_w,
                              int* __restrict__ counts) {
  const int t = blockIdx.x;
  const int lane = threadIdx.x;  // 64 threads
  float acc[NEXP];
#pragma unroll
  for (int e = 0; e < NEXP; e++) acc[e] = 0.f;
  const float* xr = x + (size_t)t * HIDDEN;
  for (int d = lane; d < HIDDEN; d += 64) {
    const float xv = xr[d];
    const float4* r = (const float4*)(rw + (size_t)d * NEXP);
#pragma unroll
    for (int q = 0; q < 4; q++) {
      float4 rv = r[q];
      acc[q * 4 + 0] += xv * rv.x;
      acc[q * 4 + 1] += xv * rv.y;
      acc[q * 4 + 2] += xv * rv.z;
      acc[q * 4 + 3] += xv * rv.w;
    }
  }
#pragma unroll
  for (int off = 32; off >= 1; off >>= 1)
#pragma unroll
    for (int e = 0; e < NEXP; e++) acc[e] += __shfl_xor(acc[e], off);

  if (lane == 0) {
    float m = acc[0];
#pragma unroll
    for (int e = 1; e < NEXP; e++) m = fmaxf(m, acc[e]);
    float p[NEXP];
    float s = 0.f;
#pragma unroll
    for (int e = 0; e < NEXP; e++) { p[e] = __expf(acc[e] - m); s += p[e]; }
    const float inv = 1.f / s;
    int i0 = 0; float p0 = p[0];
#pragma unroll
    for (int e = 1; e < NEXP; e++) if (p[e] > p0) { p0 = p[e]; i0 = e; }
    int i1 = -1; float p1 = -1.f;
#pragma unroll
    for (int e = 0; e < NEXP; e++) if (e != i0 && p[e] > p1) { p1 = p[e]; i1 = e; }
    topk_idx[t * 2 + 0] = i0;
    topk_idx[t * 2 + 1] = i1;
    topk_w[t * 2 + 0] = p0 * inv;
    topk_w[t * 2 + 1] = p1 * inv;
    atomicAdd(&counts[i0], 1);
    atomicAdd(&counts[i1], 1);
  }
}

__global__ void offsets_kernel(const int* __restrict__ counts, int* __restrict__ offs,
                               int* __restrict__ cursors) {
  if (threadIdx.x == 0) {
    int run = 0;
    for (int e = 0; e < NEXP; e++) { offs[e] = run; run += counts[e]; }
    offs[NEXP] = run;
  }
  if (threadIdx.x < NEXP) cursors[threadIdx.x] = 0;
}

__global__ void build_slots_kernel(const int* __restrict__ topk_idx, const float* __restrict__ topk_w,
                                   const int* __restrict__ offs, int* __restrict__ cursors,
                                   int* __restrict__ slot_token, float* __restrict__ slot_w) {
  const int t = blockIdx.x * blockDim.x + threadIdx.x;
  if (t >= TOKENS) return;
#pragma unroll
  for (int i = 0; i < 2; i++) {
    const int e = topk_idx[t * 2 + i];
    const int pos = atomicAdd(&cursors[e], 1);
    const int slot = offs[e] + pos;
    slot_token[slot] = t;
    slot_w[slot] = topk_w[t * 2 + i];
  }
}

// ---------------- conversions ----------------
__global__ void convert_kernel(const float* __restrict__ in, unsigned short* __restrict__ out, int n) {
  const int i = (blockIdx.x * blockDim.x + threadIdx.x) * 4;
  if (i >= n) return;
  const float4 v = *(const float4*)(in + i);
  ushort4 o;
  o.x = f2bf(v.x); o.y = f2bf(v.y); o.z = f2bf(v.z); o.w = f2bf(v.w);
  *(ushort4*)(out + i) = o;
}

// in: [B][K][N] f32 -> out: [B][N][K] bf16
__global__ void transpose_convert_kernel(const float* __restrict__ in, unsigned short* __restrict__ out,
                                         int K, int N) {
  __shared__ float tile[32][33];
  const int b = blockIdx.z;
  const int k0 = blockIdx.x * 32, n0 = blockIdx.y * 32;
  const float* src = in + (size_t)b * K * N;
  unsigned short* dst = out + (size_t)b * K * N;
  const int tx = threadIdx.x & 31, ty = threadIdx.x >> 5;  // 256 threads
#pragma unroll
  for (int r = 0; r < 32; r += 8)
    tile[ty + r][tx] = src[(size_t)(k0 + ty + r) * N + n0 + tx];
  __syncthreads();
#pragma unroll
  for (int r = 0; r < 32; r += 8)
    dst[(size_t)(n0 + ty + r) * K + k0 + tx] = f2bf(tile[tx][ty + r]);
}

// ---------------- elementwise SwiGLU combine ----------------
__global__ void silu_mul_kernel(const unsigned short* __restrict__ g, const unsigned short* __restrict__ u,
                                unsigned short* __restrict__ out, int n) {
  const int i = (blockIdx.x * blockDim.x + threadIdx.x) * 4;
  if (i >= n) return;
  const ushort4 gv = *(const ushort4*)(g + i);
  const ushort4 uv = *(const ushort4*)(u + i);
  ushort4 o;
  {
    float gf = bf2f(gv.x), uf = bf2f(uv.x);
    o.x = f2bf(gf / (1.f + __expf(-gf)) * uf);
  }
  {
    float gf = bf2f(gv.y), uf = bf2f(uv.y);
    o.y = f2bf(gf / (1.f + __expf(-gf)) * uf);
  }
  {
    float gf = bf2f(gv.z), uf = bf2f(uv.z);
    o.z = f2bf(gf / (1.f + __expf(-gf)) * uf);
  }
  {
    float gf = bf2f(gv.w), uf = bf2f(uv.w);
    o.w = f2bf(gf / (1.f + __expf(-gf)) * uf);
  }
  *(ushort4*)(out + i) = o;
}

// slot variant: scales by per-slot routing weight (folds combine weight into inter)
__global__ void silu_mul_slots_kernel(const unsigned short* __restrict__ g, const unsigned short* __restrict__ u,
                                      const float* __restrict__ slot_w, unsigned short* __restrict__ out) {
  const int i = (blockIdx.x * blockDim.x + threadIdx.x) * 4;  // over NSLOTS*DFF_E
  if (i >= NSLOTS * DFF_E) return;
  const float w = slot_w[i >> 9];  // /512, 4 consecutive share a slot
  const ushort4 gv = *(const ushort4*)(g + i);
  const ushort4 uv = *(const ushort4*)(u + i);
  ushort4 o;
  {
    float gf = bf2f(gv.x), uf = bf2f(uv.x);
    o.x = f2bf(w * gf / (1.f + __expf(-gf)) * uf);
  }
  {
    float gf = bf2f(gv.y), uf = bf2f(uv.y);
    o.y = f2bf(w * gf / (1.f + __expf(-gf)) * uf);
  }
  {
    float gf = bf2f(gv.z), uf = bf2f(uv.z);
    o.z = f2bf(w * gf / (1.f + __expf(-gf)) * uf);
  }
  {
    float gf = bf2f(gv.w), uf = bf2f(uv.w);
    o.w = f2bf(w * gf / (1.f + __expf(-gf)) * uf);
  }
  *(ushort4*)(out + i) = o;
}

// ---------------- GEMM: C[M,N] = A[M,K] * B^T[N,K], bf16 in, fp32 accum ----------------
// MODE 0: plain, write bf16 C
// MODE 1: plain, write fp32 C
// MODE 2: gather A rows via slot_token (A = x_bf16), per-expert B (blockIdx.z), write bf16 C rows=slots
// MODE 3: A rows = slots directly, per-expert B, atomicAdd fp32 into C[token][col]
template <int MODE>
__global__ __launch_bounds__(256) void gemm_bt_k(const unsigned short* __restrict__ A,
                                                 const unsigned short* __restrict__ B,
                                                 void* __restrict__ Cp, int M, int N, int K,
                                                 const int* __restrict__ offs,
                                                 const int* __restrict__ slot_token) {
  __shared__ __align__(16) unsigned short As[128 * 32];
  __shared__ __align__(16) unsigned short Bs[128 * 32];
  const int tid = threadIdx.x;
  const int lane = tid & 63;
  const int wid = tid >> 6;
  const int wr = wid >> 1, wc = wid & 1;
  const int fr = lane & 15, fq = lane >> 4;

  int rowBase, rowEnd;
  const unsigned short* Bp = B;
  if constexpr (MODE >= 2) {
    const int e = blockIdx.z;
    const int o0 = offs[e], o1 = offs[e + 1];
    rowBase = o0 + blockIdx.x * 128;
    if (rowBase >= o1) return;
    rowEnd = o1;
    Bp += (size_t)e * (size_t)N * (size_t)K;
  } else {
    rowBase = blockIdx.x * 128;
    rowEnd = M;
  }
  const int colBase = blockIdx.y * 128;

  const int rA = tid >> 2;          // staging row within tile (0..63; +64 for 2nd issue)
  const int kOff = (tid & 3) * 8;   // element offset in the 32-wide K slab
  const unsigned short *aRow0, *aRow1;
  {
    const int r0 = rowBase + rA, r1 = rowBase + rA + 64;
    if constexpr (MODE == 2) {
      const int s0 = r0 < NSLOTS ? r0 : NSLOTS - 1;
      const int s1 = r1 < NSLOTS ? r1 : NSLOTS - 1;
      aRow0 = A + (size_t)slot_token[s0] * (size_t)K;
      aRow1 = A + (size_t)slot_token[s1] * (size_t)K;
    } else {
      const int m0 = r0 < M ? r0 : M - 1;
      const int m1 = r1 < M ? r1 : M - 1;
      aRow0 = A + (size_t)m0 * (size_t)K;
      aRow1 = A + (size_t)m1 * (size_t)K;
    }
  }
  const unsigned short* bRow0 = Bp + (size_t)(colBase + rA) * (size_t)K;
  const unsigned short* bRow1 = Bp + (size_t)(colBase + rA + 64) * (size_t)K;

  unsigned short* AsW0 = As + tid * 8;
  unsigned short* AsW1 = As + 2048 + tid * 8;
  unsigned short* BsW0 = Bs + tid * 8;
  unsigned short* BsW1 = Bs + 2048 + tid * 8;

  f32x4 acc[4][4];
#pragma unroll
  for (int i = 0; i < 4; i++)
#pragma unroll
    for (int j = 0; j < 4; j++) acc[i][j] = (f32x4){0.f, 0.f, 0.f, 0.f};

  const unsigned short* AsR = As + (wr * 64 + fr) * 32 + fq * 8;
  const unsigned short* BsR = Bs + (wc * 64 + fr) * 32 + fq * 8;

  for (int k0 = 0; k0 < K; k0 += 32) {
    __syncthreads();  // previous iter's ds_reads done before overwrite
    gload16(aRow0 + k0 + kOff, AsW0);
    gload16(aRow1 + k0 + kOff, AsW1);
    gload16(bRow0 + k0 + kOff, BsW0);
    gload16(bRow1 + k0 + kOff, BsW1);
    __syncthreads();  // compiler drains vmcnt before barrier
    bf16x8 af[4], bfr[4];
#pragma unroll
    for (int m = 0; m < 4; m++) af[m] = *(const bf16x8*)(AsR + m * 512);
#pragma unroll
    for (int n = 0; n < 4; n++) bfr[n] = *(const bf16x8*)(BsR + n * 512);
#pragma unroll
    for (int m = 0; m < 4; m++)
#pragma unroll
      for (int n = 0; n < 4; n++)
        acc[m][n] = __builtin_amdgcn_mfma_f32_16x16x32_bf16(af[m], bfr[n], acc[m][n], 0, 0, 0);
  }

#pragma unroll
  for (int m = 0; m < 4; m++) {
    const int rb = rowBase + wr * 64 + m * 16 + fq * 4;
#pragma unroll
    for (int n = 0; n < 4; n++) {
      const int col = colBase + wc * 64 + n * 16 + fr;
#pragma unroll
      for (int j = 0; j < 4; j++) {
        const int r = rb + j;
        if constexpr (MODE >= 2) {
          if (r >= rowEnd) continue;
        }
        const float v = acc[m][n][j];
        if constexpr (MODE == 0) {
          ((unsigned short*)Cp)[(size_t)r * N + col] = f2bf(v);
        } else if constexpr (MODE == 1) {
          ((float*)Cp)[(size_t)r * N + col] = v;
        } else if constexpr (MODE == 2) {
          ((unsigned short*)Cp)[(size_t)r * N + col] = f2bf(v);
        } else {
          const int tok = slot_token[r];
          atomicAdd(((float*)Cp) + (size_t)tok * HIDDEN + col, v);
        }
      }
    }
  }
}

// ---------------- workspace layout (bytes) ----------------
#define WS_XB 0ull                       // 4096*1024*2      = 8388608
#define WS_WEG 8388608ull                // 16*512*1024*2    = 16777216
#define WS_WEU 25165824ull               // 16777216
#define WS_WED 41943040ull               // 16*1024*512*2    = 16777216
#define WS_WSG 58720256ull               // 2048*1024*2      = 4194304
#define WS_WSU 62914560ull               // 4194304
#define WS_WSD 67108864ull               // 1024*2048*2      = 4194304
#define WS_GBUF 71303168ull              // 4096*2048*2      = 16777216 (reused: g_slot, u_slot)
#define WS_UBUF 88080384ull              // 16777216          (reused: inter_slot)
#define WS_INTERB 104857600ull           // 16777216
#define WS_SLOT_TOKEN 121634816ull       // 8192*4
#define WS_SLOT_W 121667584ull           // 8192*4
#define WS_TOPK_IDX 121700352ull         // 8192*4
#define WS_TOPK_W 121733120ull           // 8192*4
#define WS_COUNTS 121765888ull           // 64
#define WS_OFFS 121765952ull             // 17*4 (padded)
#define WS_CURSORS 121766080ull          // 64
#define WS_NEEDED 121766144ull

extern "C" void kernel_launch(void* const* d_in, const int* in_sizes, int n_in,
                              void* d_out, int out_size, void* d_ws, size_t ws_size,
                              hipStream_t stream) {
  if (ws_size < WS_NEEDED) return;  // workspace too small; fail visibly via absmax

  const float* x = (const float*)d_in[0];
  const float* router_w = (const float*)d_in[1];
  const float* eg = (const float*)d_in[2];
  const float* eu = (const float*)d_in[3];
  const float* ed = (const float*)d_in[4];
  const float* sg = (const float*)d_in[5];
  const float* su = (const float*)d_in[6];
  const float* sd = (const float*)d_in[7];

  char* ws = (char*)d_ws;
  unsigned short* xb = (unsigned short*)(ws + WS_XB);
  unsigned short* weg = (unsigned short*)(ws + WS_WEG);
  unsigned short* weu = (unsigned short*)(ws + WS_WEU);
  unsigned short* wed = (unsigned short*)(ws + WS_WED);
  unsigned short* wsg = (unsigned short*)(ws + WS_WSG);
  unsigned short* wsu = (unsigned short*)(ws + WS_WSU);
  unsigned short* wsd = (unsigned short*)(ws + WS_WSD);
  unsigned short* gbuf = (unsigned short*)(ws + WS_GBUF);
  unsigned short* ubuf = (unsigned short*)(ws + WS_UBUF);
  unsigned short* interb = (unsigned short*)(ws + WS_INTERB);
  unsigned short* gslot = (unsigned short*)(ws + WS_GBUF);             // reuse after interb built
  unsigned short* uslot = (unsigned short*)(ws + WS_GBUF + 8388608ull);
  unsigned short* inters = (unsigned short*)(ws + WS_UBUF);            // reuse
  int* slot_token = (int*)(ws + WS_SLOT_TOKEN);
  float* slot_w = (float*)(ws + WS_SLOT_W);
  int* topk_idx = (int*)(ws + WS_TOPK_IDX);
  float* topk_w = (float*)(ws + WS_TOPK_W);
  int* counts = (int*)(ws + WS_COUNTS);
  int* offs = (int*)(ws + WS_OFFS);
  int* cursors = (int*)(ws + WS_CURSORS);

  float* out = (float*)d_out;

  // --- routing (fp32, selection-exact) ---
  hipMemsetAsync(counts, 0, NEXP * sizeof(int), stream);
  router_kernel<<<TOKENS, 64, 0, stream>>>(x, router_w, topk_idx, topk_w, counts);
  offsets_kernel<<<1, 64, 0, stream>>>(counts, offs, cursors);
  build_slots_kernel<<<16, 256, 0, stream>>>(topk_idx, topk_w, offs, cursors, slot_token, slot_w);

  // --- bf16 conversions (weights transposed to [N,K]) ---
  convert_kernel<<<4096, 256, 0, stream>>>(x, xb, TOKENS * HIDDEN);
  transpose_convert_kernel<<<dim3(32, 16, 16), 256, 0, stream>>>(eg, weg, 1024, 512);
  transpose_convert_kernel<<<dim3(32, 16, 16), 256, 0, stream>>>(eu, weu, 1024, 512);
  transpose_convert_kernel<<<dim3(16, 32, 16), 256, 0, stream>>>(ed, wed, 512, 1024);
  transpose_convert_kernel<<<dim3(32, 64, 1), 256, 0, stream>>>(sg, wsg, 1024, 2048);
  transpose_convert_kernel<<<dim3(32, 64, 1), 256, 0, stream>>>(su, wsu, 1024, 2048);
  transpose_convert_kernel<<<dim3(64, 32, 1), 256, 0, stream>>>(sd, wsd, 2048, 1024);

  // --- shared expert: gate/up GEMMs -> silu*mul -> down GEMM (writes all of d_out) ---
  gemm_bt_k<0><<<dim3(32, 16, 1), 256, 0, stream>>>(xb, wsg, gbuf, 4096, 2048, 1024, nullptr, nullptr);
  gemm_bt_k<0><<<dim3(32, 16, 1), 256, 0, stream>>>(xb, wsu, ubuf, 4096, 2048, 1024, nullptr, nullptr);
  silu_mul_kernel<<<8192, 256, 0, stream>>>(gbuf, ubuf, interb, 4096 * 2048);
  gemm_bt_k<1><<<dim3(32, 8, 1), 256, 0, stream>>>(interb, wsd, out, 4096, 1024, 2048, nullptr, nullptr);

  // --- routed experts: gathered gate/up -> silu*mul*w -> down + scatter-add ---
  gemm_bt_k<2><<<dim3(32, 4, 16), 256, 0, stream>>>(xb, weg, gslot, NSLOTS, 512, 1024, offs, slot_token);
  gemm_bt_k<2><<<dim3(32, 4, 16), 256, 0, stream>>>(xb, weu, uslot, NSLOTS, 512, 1024, offs, slot_token);
  silu_mul_slots_kernel<<<4096, 256, 0, stream>>>(gslot, uslot, slot_w, inters);
  gemm_bt_k<3><<<dim3(32, 8, 16), 256, 0, stream>>>(inters, wed, out, NSLOTS, 1024, 512, offs, slot_token);
}

// Round 2
// 684.910 us; speedup vs baseline: 1.1570x; 1.1570x over previous
//
#include <hip/hip_runtime.h>
#include <hip/hip_bf16.h>
#include <stdint.h>

#define HIDDEN 1024
#define NEXP 16
#define DFF_E 512
#define DFF_S 2048
#define TOKENS 4096
#define NSLOTS 8192  // TOKENS * TOP_K

typedef __bf16 bf16x8 __attribute__((ext_vector_type(8)));
typedef float f32x4 __attribute__((ext_vector_type(4)));

__device__ __forceinline__ unsigned short f2bf(float f) {
  unsigned int u = __builtin_bit_cast(unsigned int, f);
  u += 0x7FFFu + ((u >> 16) & 1u);
  return (unsigned short)(u >> 16);
}
__device__ __forceinline__ float bf2f(unsigned short h) {
  unsigned int u = ((unsigned int)h) << 16;
  return __builtin_bit_cast(float, u);
}
__device__ __forceinline__ void gload16(const void* g, void* l) {
  __builtin_amdgcn_global_load_lds(
      (const __attribute__((address_space(1))) unsigned int*)g,
      (__attribute__((address_space(3))) unsigned int*)l, 16, 0, 0);
}

// ---------------- router: fp32 logits -> softmax -> top2 ----------------
__global__ void router_kernel(const float* __restrict__ x, const float* __restrict__ rw,
                              int* __restrict__ topk_idx, float* __restrict__ topk_w,
                              int* __restrict__ counts) {
  const int t = blockIdx.x;
  const int lane = threadIdx.x;  // 64 threads
  float acc[NEXP];
#pragma unroll
  for (int e = 0; e < NEXP; e++) acc[e] = 0.f;
  const float* xr = x + (size_t)t * HIDDEN;
  for (int d = lane; d < HIDDEN; d += 64) {
    const float xv = xr[d];
    const float4* r = (const float4*)(rw + (size_t)d * NEXP);
#pragma unroll
    for (int q = 0; q < 4; q++) {
      float4 rv = r[q];
      acc[q * 4 + 0] += xv * rv.x;
      acc[q * 4 + 1] += xv * rv.y;
      acc[q * 4 + 2] += xv * rv.z;
      acc[q * 4 + 3] += xv * rv.w;
    }
  }
#pragma unroll
  for (int off = 32; off >= 1; off >>= 1)
#pragma unroll
    for (int e = 0; e < NEXP; e++) acc[e] += __shfl_xor(acc[e], off);

  if (lane == 0) {
    float m = acc[0];
#pragma unroll
    for (int e = 1; e < NEXP; e++) m = fmaxf(m, acc[e]);
    float p[NEXP];
    float s = 0.f;
#pragma unroll
    for (int e = 0; e < NEXP; e++) { p[e] = __expf(acc[e] - m); s += p[e]; }
    const float inv = 1.f / s;
    int i0 = 0; float p0 = p[0];
#pragma unroll
    for (int e = 1; e < NEXP; e++) if (p[e] > p0) { p0 = p[e]; i0 = e; }
    int i1 = -1; float p1 = -1.f;
#pragma unroll
    for (int e = 0; e < NEXP; e++) if (e != i0 && p[e] > p1) { p1 = p[e]; i1 = e; }
    topk_idx[t * 2 + 0] = i0;
    topk_idx[t * 2 + 1] = i1;
    topk_w[t * 2 + 0] = p0 * inv;
    topk_w[t * 2 + 1] = p1 * inv;
    atomicAdd(&counts[i0], 1);
    atomicAdd(&counts[i1], 1);
  }
}

__global__ void offsets_kernel(const int* __restrict__ counts, int* __restrict__ offs,
                               int* __restrict__ cursors) {
  if (threadIdx.x == 0) {
    int run = 0;
    for (int e = 0; e < NEXP; e++) { offs[e] = run; run += counts[e]; }
    offs[NEXP] = run;
  }
  if (threadIdx.x < NEXP) cursors[threadIdx.x] = 0;
}

__global__ void build_slots_kernel(const int* __restrict__ topk_idx, const float* __restrict__ topk_w,
                                   const int* __restrict__ offs, int* __restrict__ cursors,
                                   int* __restrict__ slot_token, float* __restrict__ slot_w,
                                   int* __restrict__ slot_pos) {
  const int t = blockIdx.x * blockDim.x + threadIdx.x;
  if (t >= TOKENS) return;
#pragma unroll
  for (int i = 0; i < 2; i++) {
    const int e = topk_idx[t * 2 + i];
    const int pos = atomicAdd(&cursors[e], 1);
    const int slot = offs[e] + pos;
    slot_token[slot] = t;
    slot_w[slot] = topk_w[t * 2 + i];
    slot_pos[t * 2 + i] = slot;
  }
}

// ---------------- conversions ----------------
__global__ void convert_kernel(const float* __restrict__ in, unsigned short* __restrict__ out, int n) {
  const int i = (blockIdx.x * blockDim.x + threadIdx.x) * 4;
  if (i >= n) return;
  const float4 v = *(const float4*)(in + i);
  ushort4 o;
  o.x = f2bf(v.x); o.y = f2bf(v.y); o.z = f2bf(v.z); o.w = f2bf(v.w);
  *(ushort4*)(out + i) = o;
}

// in: [B][K][N] f32 -> out: [B][N][K] bf16
__global__ void transpose_convert_kernel(const float* __restrict__ in, unsigned short* __restrict__ out,
                                         int K, int N) {
  __shared__ float tile[32][33];
  const int b = blockIdx.z;
  const int k0 = blockIdx.x * 32, n0 = blockIdx.y * 32;
  const float* src = in + (size_t)b * K * N;
  unsigned short* dst = out + (size_t)b * K * N;
  const int tx = threadIdx.x & 31, ty = threadIdx.x >> 5;  // 256 threads
#pragma unroll
  for (int r = 0; r < 32; r += 8)
    tile[ty + r][tx] = src[(size_t)(k0 + ty + r) * N + n0 + tx];
  __syncthreads();
#pragma unroll
  for (int r = 0; r < 32; r += 8)
    dst[(size_t)(n0 + ty + r) * K + k0 + tx] = f2bf(tile[tx][ty + r]);
}

// ---------------- fused gate+up+SiLU GEMM ----------------
// C[M,N] = silu(A*Bg^T) * (A*Bu^T)  (optionally * slot_w[row]), bf16 out.
// GATHER=0: plain rows (shared expert). GATHER=1: A rows gathered via slot_token,
// per-expert Bg/Bu via blockIdx.z, rows restricted to [offs[e], offs[e+1]).
template <int GATHER>
__global__ __launch_bounds__(256) void fused_gu_k(const unsigned short* __restrict__ A,
                                                  const unsigned short* __restrict__ Bg,
                                                  const unsigned short* __restrict__ Bu,
                                                  unsigned short* __restrict__ C,
                                                  int M, int N, int K,
                                                  const int* __restrict__ offs,
                                                  const int* __restrict__ slot_token,
                                                  const float* __restrict__ slot_w) {
  __shared__ __align__(16) unsigned short As[128 * 32];
  __shared__ __align__(16) unsigned short Bgs[128 * 32];
  __shared__ __align__(16) unsigned short Bus[128 * 32];
  const int tid = threadIdx.x;
  const int lane = tid & 63;
  const int wid = tid >> 6;
  const int wr = wid >> 1, wc = wid & 1;
  const int fr = lane & 15, fq = lane >> 4;

  int rowBase, rowEnd;
  const unsigned short* Bgp = Bg;
  const unsigned short* Bup = Bu;
  if constexpr (GATHER) {
    const int e = blockIdx.z;
    const int o0 = offs[e], o1 = offs[e + 1];
    rowBase = o0 + blockIdx.x * 128;
    if (rowBase >= o1) return;
    rowEnd = o1;
    Bgp += (size_t)e * (size_t)N * (size_t)K;
    Bup += (size_t)e * (size_t)N * (size_t)K;
  } else {
    rowBase = blockIdx.x * 128;
    rowEnd = M;
  }
  const int colBase = blockIdx.y * 128;

  const int rA = tid >> 2;
  const int kOff = (tid & 3) * 8;
  const unsigned short *aRow0, *aRow1;
  {
    const int r0 = rowBase + rA, r1 = rowBase + rA + 64;
    if constexpr (GATHER) {
      const int s0 = r0 < NSLOTS ? r0 : NSLOTS - 1;
      const int s1 = r1 < NSLOTS ? r1 : NSLOTS - 1;
      aRow0 = A + (size_t)slot_token[s0] * (size_t)K;
      aRow1 = A + (size_t)slot_token[s1] * (size_t)K;
    } else {
      const int m0 = r0 < M ? r0 : M - 1;
      const int m1 = r1 < M ? r1 : M - 1;
      aRow0 = A + (size_t)m0 * (size_t)K;
      aRow1 = A + (size_t)m1 * (size_t)K;
    }
  }
  const unsigned short* bgRow0 = Bgp + (size_t)(colBase + rA) * (size_t)K;
  const unsigned short* bgRow1 = Bgp + (size_t)(colBase + rA + 64) * (size_t)K;
  const unsigned short* buRow0 = Bup + (size_t)(colBase + rA) * (size_t)K;
  const unsigned short* buRow1 = Bup + (size_t)(colBase + rA + 64) * (size_t)K;

  f32x4 accg[4][4], accu[4][4];
#pragma unroll
  for (int i = 0; i < 4; i++)
#pragma unroll
    for (int j = 0; j < 4; j++) {
      accg[i][j] = (f32x4){0.f, 0.f, 0.f, 0.f};
      accu[i][j] = (f32x4){0.f, 0.f, 0.f, 0.f};
    }

  const unsigned short* AsR = As + (wr * 64 + fr) * 32 + fq * 8;
  const unsigned short* BgsR = Bgs + (wc * 64 + fr) * 32 + fq * 8;
  const unsigned short* BusR = Bus + (wc * 64 + fr) * 32 + fq * 8;

  for (int k0 = 0; k0 < K; k0 += 32) {
    __syncthreads();
    gload16(aRow0 + k0 + kOff, As + tid * 8);
    gload16(aRow1 + k0 + kOff, As + 2048 + tid * 8);
    gload16(bgRow0 + k0 + kOff, Bgs + tid * 8);
    gload16(bgRow1 + k0 + kOff, Bgs + 2048 + tid * 8);
    gload16(buRow0 + k0 + kOff, Bus + tid * 8);
    gload16(buRow1 + k0 + kOff, Bus + 2048 + tid * 8);
    __syncthreads();
    bf16x8 af[4], bgf[4], buf[4];
#pragma unroll
    for (int m = 0; m < 4; m++) af[m] = *(const bf16x8*)(AsR + m * 512);
#pragma unroll
    for (int n = 0; n < 4; n++) bgf[n] = *(const bf16x8*)(BgsR + n * 512);
#pragma unroll
    for (int n = 0; n < 4; n++) buf[n] = *(const bf16x8*)(BusR + n * 512);
#pragma unroll
    for (int m = 0; m < 4; m++)
#pragma unroll
      for (int n = 0; n < 4; n++) {
        accg[m][n] = __builtin_amdgcn_mfma_f32_16x16x32_bf16(af[m], bgf[n], accg[m][n], 0, 0, 0);
        accu[m][n] = __builtin_amdgcn_mfma_f32_16x16x32_bf16(af[m], buf[n], accu[m][n], 0, 0, 0);
      }
  }

#pragma unroll
  for (int m = 0; m < 4; m++) {
    const int rb = rowBase + wr * 64 + m * 16 + fq * 4;
#pragma unroll
    for (int n = 0; n < 4; n++) {
      const int col = colBase + wc * 64 + n * 16 + fr;
#pragma unroll
      for (int j = 0; j < 4; j++) {
        const int r = rb + j;
        if constexpr (GATHER) {
          if (r >= rowEnd) continue;
        }
        const float g = accg[m][n][j];
        const float u = accu[m][n][j];
        float v = g / (1.f + __expf(-g)) * u;
        if constexpr (GATHER) v *= slot_w[r];
        C[(size_t)r * N + col] = f2bf(v);
      }
    }
  }
}

// ---------------- down-projection GEMM: C = A * B^T ----------------
// EXPERT=0: plain, write fp32 C (shared path final output).
// EXPERT=1: per-expert B via blockIdx.z, rows = slots in [offs[e],offs[e+1]),
//           write bf16 per-slot rows (combined later).
template <int EXPERT>
__global__ __launch_bounds__(256) void down_gemm_k(const unsigned short* __restrict__ A,
                                                   const unsigned short* __restrict__ B,
                                                   void* __restrict__ Cp, int M, int N, int K,
                                                   const int* __restrict__ offs) {
  __shared__ __align__(16) unsigned short As[128 * 32];
  __shared__ __align__(16) unsigned short Bs[128 * 32];
  const int tid = threadIdx.x;
  const int lane = tid & 63;
  const int wid = tid >> 6;
  const int wr = wid >> 1, wc = wid & 1;
  const int fr = lane & 15, fq = lane >> 4;

  int rowBase, rowEnd;
  const unsigned short* Bp = B;
  if constexpr (EXPERT) {
    const int e = blockIdx.z;
    const int o0 = offs[e], o1 = offs[e + 1];
    rowBase = o0 + blockIdx.x * 128;
    if (rowBase >= o1) return;
    rowEnd = o1;
    Bp += (size_t)e * (size_t)N * (size_t)K;
  } else {
    rowBase = blockIdx.x * 128;
    rowEnd = M;
  }
  const int colBase = blockIdx.y * 128;

  const int rA = tid >> 2;
  const int kOff = (tid & 3) * 8;
  const int maxRow = (EXPERT ? NSLOTS : M) - 1;
  const int r0 = min(rowBase + rA, maxRow);
  const int r1 = min(rowBase + rA + 64, maxRow);
  const unsigned short* aRow0 = A + (size_t)r0 * (size_t)K;
  const unsigned short* aRow1 = A + (size_t)r1 * (size_t)K;
  const unsigned short* bRow0 = Bp + (size_t)(colBase + rA) * (size_t)K;
  const unsigned short* bRow1 = Bp + (size_t)(colBase + rA + 64) * (size_t)K;

  f32x4 acc[4][4];
#pragma unroll
  for (int i = 0; i < 4; i++)
#pragma unroll
    for (int j = 0; j < 4; j++) acc[i][j] = (f32x4){0.f, 0.f, 0.f, 0.f};

  const unsigned short* AsR = As + (wr * 64 + fr) * 32 + fq * 8;
  const unsigned short* BsR = Bs + (wc * 64 + fr) * 32 + fq * 8;

  for (int k0 = 0; k0 < K; k0 += 32) {
    __syncthreads();
    gload16(aRow0 + k0 + kOff, As + tid * 8);
    gload16(aRow1 + k0 + kOff, As + 2048 + tid * 8);
    gload16(bRow0 + k0 + kOff, Bs + tid * 8);
    gload16(bRow1 + k0 + kOff, Bs + 2048 + tid * 8);
    __syncthreads();
    bf16x8 af[4], bfr[4];
#pragma unroll
    for (int m = 0; m < 4; m++) af[m] = *(const bf16x8*)(AsR + m * 512);
#pragma unroll
    for (int n = 0; n < 4; n++) bfr[n] = *(const bf16x8*)(BsR + n * 512);
#pragma unroll
    for (int m = 0; m < 4; m++)
#pragma unroll
      for (int n = 0; n < 4; n++)
        acc[m][n] = __builtin_amdgcn_mfma_f32_16x16x32_bf16(af[m], bfr[n], acc[m][n], 0, 0, 0);
  }

#pragma unroll
  for (int m = 0; m < 4; m++) {
    const int rb = rowBase + wr * 64 + m * 16 + fq * 4;
#pragma unroll
    for (int n = 0; n < 4; n++) {
      const int col = colBase + wc * 64 + n * 16 + fr;
#pragma unroll
      for (int j = 0; j < 4; j++) {
        const int r = rb + j;
        if constexpr (EXPERT) {
          if (r >= rowEnd) continue;
          ((unsigned short*)Cp)[(size_t)r * N + col] = f2bf(acc[m][n][j]);
        } else {
          ((float*)Cp)[(size_t)r * N + col] = acc[m][n][j];
        }
      }
    }
  }
}

// ---------------- final combine: out[t] += dslot[s0[t]] + dslot[s1[t]] ----------------
__global__ void combine_kernel(float* __restrict__ out, const unsigned short* __restrict__ dslot,
                               const int* __restrict__ slot_pos) {
  const int t = blockIdx.x;
  const int s0 = slot_pos[t * 2 + 0];
  const int s1 = slot_pos[t * 2 + 1];
  const int c = threadIdx.x * 4;
  const ushort4 a = *(const ushort4*)(dslot + (size_t)s0 * HIDDEN + c);
  const ushort4 b = *(const ushort4*)(dslot + (size_t)s1 * HIDDEN + c);
  float4* o = (float4*)(out + (size_t)t * HIDDEN + c);
  float4 v = *o;
  v.x += bf2f(a.x) + bf2f(b.x);
  v.y += bf2f(a.y) + bf2f(b.y);
  v.z += bf2f(a.z) + bf2f(b.z);
  v.w += bf2f(a.w) + bf2f(b.w);
  *o = v;
}

// ---------------- workspace layout (bytes) ----------------
#define WS_XB 0ull                 // 4096*1024*2   = 8388608
#define WS_WEG 8388608ull          // 16*512*1024*2 = 16777216
#define WS_WEU 25165824ull         // 16777216
#define WS_WED 41943040ull         // 16*1024*512*2 = 16777216
#define WS_WSG 58720256ull         // 2048*1024*2   = 4194304
#define WS_WSU 62914560ull         // 4194304
#define WS_WSD 67108864ull         // 4194304
#define WS_INTERB 71303168ull      // 4096*2048*2   = 16777216
#define WS_INTERS 88080384ull      // 8192*512*2    = 8388608
#define WS_DSLOT 96468992ull       // 8192*1024*2   = 16777216
#define WS_SLOT_TOKEN 113246208ull // 8192*4
#define WS_SLOT_W 113278976ull     // 8192*4
#define WS_SLOT_POS 113311744ull   // 8192*4
#define WS_TOPK_IDX 113344512ull   // 8192*4
#define WS_TOPK_W 113377280ull     // 8192*4
#define WS_COUNTS 113410048ull     // 64
#define WS_OFFS 113410112ull       // 128
#define WS_CURSORS 113410240ull    // 64
#define WS_NEEDED 113410304ull

extern "C" void kernel_launch(void* const* d_in, const int* in_sizes, int n_in,
                              void* d_out, int out_size, void* d_ws, size_t ws_size,
                              hipStream_t stream) {
  if (ws_size < WS_NEEDED) return;

  const float* x = (const float*)d_in[0];
  const float* router_w = (const float*)d_in[1];
  const float* eg = (const float*)d_in[2];
  const float* eu = (const float*)d_in[3];
  const float* ed = (const float*)d_in[4];
  const float* sg = (const float*)d_in[5];
  const float* su = (const float*)d_in[6];
  const float* sd = (const float*)d_in[7];

  char* ws = (char*)d_ws;
  unsigned short* xb = (unsigned short*)(ws + WS_XB);
  unsigned short* weg = (unsigned short*)(ws + WS_WEG);
  unsigned short* weu = (unsigned short*)(ws + WS_WEU);
  unsigned short* wed = (unsigned short*)(ws + WS_WED);
  unsigned short* wsg = (unsigned short*)(ws + WS_WSG);
  unsigned short* wsu = (unsigned short*)(ws + WS_WSU);
  unsigned short* wsd = (unsigned short*)(ws + WS_WSD);
  unsigned short* interb = (unsigned short*)(ws + WS_INTERB);
  unsigned short* inters = (unsigned short*)(ws + WS_INTERS);
  unsigned short* dslot = (unsigned short*)(ws + WS_DSLOT);
  int* slot_token = (int*)(ws + WS_SLOT_TOKEN);
  float* slot_w = (float*)(ws + WS_SLOT_W);
  int* slot_pos = (int*)(ws + WS_SLOT_POS);
  int* topk_idx = (int*)(ws + WS_TOPK_IDX);
  float* topk_w = (float*)(ws + WS_TOPK_W);
  int* counts = (int*)(ws + WS_COUNTS);
  int* offs = (int*)(ws + WS_OFFS);
  int* cursors = (int*)(ws + WS_CURSORS);

  float* out = (float*)d_out;

  // --- routing (fp32, selection-exact) ---
  hipMemsetAsync(counts, 0, NEXP * sizeof(int), stream);
  router_kernel<<<TOKENS, 64, 0, stream>>>(x, router_w, topk_idx, topk_w, counts);
  offsets_kernel<<<1, 64, 0, stream>>>(counts, offs, cursors);
  build_slots_kernel<<<16, 256, 0, stream>>>(topk_idx, topk_w, offs, cursors,
                                             slot_token, slot_w, slot_pos);

  // --- bf16 conversions (weights transposed to [N,K]) ---
  convert_kernel<<<4096, 256, 0, stream>>>(x, xb, TOKENS * HIDDEN);
  transpose_convert_kernel<<<dim3(32, 16, 16), 256, 0, stream>>>(eg, weg, 1024, 512);
  transpose_convert_kernel<<<dim3(32, 16, 16), 256, 0, stream>>>(eu, weu, 1024, 512);
  transpose_convert_kernel<<<dim3(16, 32, 16), 256, 0, stream>>>(ed, wed, 512, 1024);
  transpose_convert_kernel<<<dim3(32, 64, 1), 256, 0, stream>>>(sg, wsg, 1024, 2048);
  transpose_convert_kernel<<<dim3(32, 64, 1), 256, 0, stream>>>(su, wsu, 1024, 2048);
  transpose_convert_kernel<<<dim3(64, 32, 1), 256, 0, stream>>>(sd, wsd, 2048, 1024);

  // --- shared expert: fused gate+up+silu -> down (writes all of d_out, fp32) ---
  fused_gu_k<0><<<dim3(32, 16, 1), 256, 0, stream>>>(xb, wsg, wsu, interb, TOKENS, DFF_S, HIDDEN,
                                                     nullptr, nullptr, nullptr);
  down_gemm_k<0><<<dim3(32, 8, 1), 256, 0, stream>>>(interb, wsd, out, TOKENS, HIDDEN, DFF_S, nullptr);

  // --- routed experts: fused gathered gate+up+silu*w -> per-slot down -> combine ---
  fused_gu_k<1><<<dim3(16, 4, 16), 256, 0, stream>>>(xb, weg, weu, inters, NSLOTS, DFF_E, HIDDEN,
                                                     offs, slot_token, slot_w);
  down_gemm_k<1><<<dim3(16, 8, 16), 256, 0, stream>>>(inters, wed, dslot, NSLOTS, HIDDEN, DFF_E, offs);
  combine_kernel<<<TOKENS, 256, 0, stream>>>(out, dslot, slot_pos);
}

// Round 3
// 644.276 us; speedup vs baseline: 1.2299x; 1.0631x over previous
//
#include <hip/hip_runtime.h>
#include <hip/hip_bf16.h>
#include <stdint.h>

#define HIDDEN 1024
#define NEXP 16
#define DFF_E 512
#define DFF_S 2048
#define TOKENS 4096
#define NSLOTS 8192  // TOKENS * TOP_K

typedef __bf16 bf16x8 __attribute__((ext_vector_type(8)));
typedef float f32x4 __attribute__((ext_vector_type(4)));

__device__ __forceinline__ unsigned short f2bf(float f) {
  unsigned int u = __builtin_bit_cast(unsigned int, f);
  u += 0x7FFFu + ((u >> 16) & 1u);
  return (unsigned short)(u >> 16);
}
__device__ __forceinline__ float bf2f(unsigned short h) {
  unsigned int u = ((unsigned int)h) << 16;
  return __builtin_bit_cast(float, u);
}
__device__ __forceinline__ void gload16(const void* g, void* l) {
  __builtin_amdgcn_global_load_lds(
      (const __attribute__((address_space(1))) unsigned int*)g,
      (__attribute__((address_space(3))) unsigned int*)l, 16, 0, 0);
}
__device__ __forceinline__ void wait_vmcnt0() {
  asm volatile("s_waitcnt vmcnt(0)" ::: "memory");
}
__device__ __forceinline__ void wait_lgkmcnt0() {
  asm volatile("s_waitcnt lgkmcnt(0)" ::: "memory");
}
__device__ __forceinline__ void hard_barrier() {
  __builtin_amdgcn_sched_barrier(0);
  __builtin_amdgcn_s_barrier();
  __builtin_amdgcn_sched_barrier(0);
}

// ---------------- router: fp32 logits -> softmax -> top2 ----------------
__global__ void router_kernel(const float* __restrict__ x, const float* __restrict__ rw,
                              int* __restrict__ topk_idx, float* __restrict__ topk_w,
                              int* __restrict__ counts) {
  const int t = blockIdx.x;
  const int lane = threadIdx.x;  // 64 threads
  float acc[NEXP];
#pragma unroll
  for (int e = 0; e < NEXP; e++) acc[e] = 0.f;
  const float* xr = x + (size_t)t * HIDDEN;
  for (int d = lane; d < HIDDEN; d += 64) {
    const float xv = xr[d];
    const float4* r = (const float4*)(rw + (size_t)d * NEXP);
#pragma unroll
    for (int q = 0; q < 4; q++) {
      float4 rv = r[q];
      acc[q * 4 + 0] += xv * rv.x;
      acc[q * 4 + 1] += xv * rv.y;
      acc[q * 4 + 2] += xv * rv.z;
      acc[q * 4 + 3] += xv * rv.w;
    }
  }
#pragma unroll
  for (int off = 32; off >= 1; off >>= 1)
#pragma unroll
    for (int e = 0; e < NEXP; e++) acc[e] += __shfl_xor(acc[e], off);

  if (lane == 0) {
    float m = acc[0];
#pragma unroll
    for (int e = 1; e < NEXP; e++) m = fmaxf(m, acc[e]);
    float p[NEXP];
    float s = 0.f;
#pragma unroll
    for (int e = 0; e < NEXP; e++) { p[e] = __expf(acc[e] - m); s += p[e]; }
    const float inv = 1.f / s;
    int i0 = 0; float p0 = p[0];
#pragma unroll
    for (int e = 1; e < NEXP; e++) if (p[e] > p0) { p0 = p[e]; i0 = e; }
    int i1 = -1; float p1 = -1.f;
#pragma unroll
    for (int e = 0; e < NEXP; e++) if (e != i0 && p[e] > p1) { p1 = p[e]; i1 = e; }
    topk_idx[t * 2 + 0] = i0;
    topk_idx[t * 2 + 1] = i1;
    topk_w[t * 2 + 0] = p0 * inv;
    topk_w[t * 2 + 1] = p1 * inv;
    atomicAdd(&counts[i0], 1);
    atomicAdd(&counts[i1], 1);
  }
}

__global__ void offsets_kernel(const int* __restrict__ counts, int* __restrict__ offs,
                               int* __restrict__ cursors) {
  if (threadIdx.x == 0) {
    int run = 0;
    for (int e = 0; e < NEXP; e++) { offs[e] = run; run += counts[e]; }
    offs[NEXP] = run;
  }
  if (threadIdx.x < NEXP) cursors[threadIdx.x] = 0;
}

__global__ void build_slots_kernel(const int* __restrict__ topk_idx, const float* __restrict__ topk_w,
                                   const int* __restrict__ offs, int* __restrict__ cursors,
                                   int* __restrict__ slot_token, float* __restrict__ slot_w,
                                   int* __restrict__ slot_pos) {
  const int t = blockIdx.x * blockDim.x + threadIdx.x;
  if (t >= TOKENS) return;
#pragma unroll
  for (int i = 0; i < 2; i++) {
    const int e = topk_idx[t * 2 + i];
    const int pos = atomicAdd(&cursors[e], 1);
    const int slot = offs[e] + pos;
    slot_token[slot] = t;
    slot_w[slot] = topk_w[t * 2 + i];
    slot_pos[t * 2 + i] = slot;
  }
}

// ---------------- conversions ----------------
__global__ void convert_kernel(const float* __restrict__ in, unsigned short* __restrict__ out, int n) {
  const int i = (blockIdx.x * blockDim.x + threadIdx.x) * 4;
  if (i >= n) return;
  const float4 v = *(const float4*)(in + i);
  ushort4 o;
  o.x = f2bf(v.x); o.y = f2bf(v.y); o.z = f2bf(v.z); o.w = f2bf(v.w);
  *(ushort4*)(out + i) = o;
}

// in: [B][K][N] f32 -> out: [B][N][K] bf16
__global__ void transpose_convert_kernel(const float* __restrict__ in, unsigned short* __restrict__ out,
                                         int K, int N) {
  __shared__ float tile[32][33];
  const int b = blockIdx.z;
  const int k0 = blockIdx.x * 32, n0 = blockIdx.y * 32;
  const float* src = in + (size_t)b * K * N;
  unsigned short* dst = out + (size_t)b * K * N;
  const int tx = threadIdx.x & 31, ty = threadIdx.x >> 5;  // 256 threads
#pragma unroll
  for (int r = 0; r < 32; r += 8)
    tile[ty + r][tx] = src[(size_t)(k0 + ty + r) * N + n0 + tx];
  __syncthreads();
#pragma unroll
  for (int r = 0; r < 32; r += 8)
    dst[(size_t)(n0 + ty + r) * K + k0 + tx] = f2bf(tile[tx][ty + r]);
}

// ---------------- fused gate+up+SiLU GEMM (2-phase double-buffered) ----------------
// C[M,N] = silu(A*Bg^T) * (A*Bu^T)  (optionally * slot_w[row]), bf16 out.
template <int GATHER>
__global__ __launch_bounds__(256) void fused_gu_k(const unsigned short* __restrict__ A,
                                                  const unsigned short* __restrict__ Bg,
                                                  const unsigned short* __restrict__ Bu,
                                                  unsigned short* __restrict__ C,
                                                  int M, int N, int K,
                                                  const int* __restrict__ offs,
                                                  const int* __restrict__ slot_token,
                                                  const float* __restrict__ slot_w) {
  __shared__ __align__(16) unsigned short As[2][4096];
  __shared__ __align__(16) unsigned short Bgs[2][4096];
  __shared__ __align__(16) unsigned short Bus[2][4096];
  const int tid = threadIdx.x;
  const int lane = tid & 63;
  const int wid = tid >> 6;
  const int wr = wid >> 1, wc = wid & 1;
  const int fr = lane & 15, fq = lane >> 4;

  int rowBase, rowEnd;
  const unsigned short* Bgp = Bg;
  const unsigned short* Bup = Bu;
  if constexpr (GATHER) {
    const int e = blockIdx.z;
    const int o0 = offs[e], o1 = offs[e + 1];
    rowBase = o0 + blockIdx.x * 128;
    if (rowBase >= o1) return;
    rowEnd = o1;
    Bgp += (size_t)e * (size_t)N * (size_t)K;
    Bup += (size_t)e * (size_t)N * (size_t)K;
  } else {
    rowBase = blockIdx.x * 128;
    rowEnd = M;
  }
  const int colBase = blockIdx.y * 128;

  const int rA = tid >> 2;
  const int kOff = (tid & 3) * 8;
  const unsigned short *aRow0, *aRow1;
  {
    const int r0 = rowBase + rA, r1 = rowBase + rA + 64;
    if constexpr (GATHER) {
      const int s0 = r0 < NSLOTS ? r0 : NSLOTS - 1;
      const int s1 = r1 < NSLOTS ? r1 : NSLOTS - 1;
      aRow0 = A + (size_t)slot_token[s0] * (size_t)K;
      aRow1 = A + (size_t)slot_token[s1] * (size_t)K;
    } else {
      const int m0 = r0 < M ? r0 : M - 1;
      const int m1 = r1 < M ? r1 : M - 1;
      aRow0 = A + (size_t)m0 * (size_t)K;
      aRow1 = A + (size_t)m1 * (size_t)K;
    }
  }
  const unsigned short* bgRow0 = Bgp + (size_t)(colBase + rA) * (size_t)K;
  const unsigned short* bgRow1 = Bgp + (size_t)(colBase + rA + 64) * (size_t)K;
  const unsigned short* buRow0 = Bup + (size_t)(colBase + rA) * (size_t)K;
  const unsigned short* buRow1 = Bup + (size_t)(colBase + rA + 64) * (size_t)K;

  f32x4 accg[4][4], accu[4][4];
#pragma unroll
  for (int i = 0; i < 4; i++)
#pragma unroll
    for (int j = 0; j < 4; j++) {
      accg[i][j] = (f32x4){0.f, 0.f, 0.f, 0.f};
      accu[i][j] = (f32x4){0.f, 0.f, 0.f, 0.f};
    }

  const int ldOff = tid * 8;
  auto stage = [&](int b, int k0) {
    gload16(aRow0 + k0 + kOff, &As[b][ldOff]);
    gload16(aRow1 + k0 + kOff, &As[b][2048 + ldOff]);
    gload16(bgRow0 + k0 + kOff, &Bgs[b][ldOff]);
    gload16(bgRow1 + k0 + kOff, &Bgs[b][2048 + ldOff]);
    gload16(buRow0 + k0 + kOff, &Bus[b][ldOff]);
    gload16(buRow1 + k0 + kOff, &Bus[b][2048 + ldOff]);
  };

  const int rdA = (wr * 64 + fr) * 32 + fq * 8;
  const int rdB = (wc * 64 + fr) * 32 + fq * 8;

  const int nsteps = K >> 5;
  int cur = 0;
  stage(0, 0);
  wait_vmcnt0();
  hard_barrier();

  for (int s = 0; s < nsteps; ++s) {
    if (s + 1 < nsteps) stage(cur ^ 1, (s + 1) << 5);
    bf16x8 af[4], bgf[4], buf_[4];
#pragma unroll
    for (int m = 0; m < 4; m++) af[m] = *(const bf16x8*)(&As[cur][rdA + m * 512]);
#pragma unroll
    for (int n = 0; n < 4; n++) bgf[n] = *(const bf16x8*)(&Bgs[cur][rdB + n * 512]);
#pragma unroll
    for (int n = 0; n < 4; n++) buf_[n] = *(const bf16x8*)(&Bus[cur][rdB + n * 512]);
    wait_lgkmcnt0();
    __builtin_amdgcn_sched_barrier(0);
#pragma unroll
    for (int m = 0; m < 4; m++)
#pragma unroll
      for (int n = 0; n < 4; n++) {
        accg[m][n] = __builtin_amdgcn_mfma_f32_16x16x32_bf16(af[m], bgf[n], accg[m][n], 0, 0, 0);
        accu[m][n] = __builtin_amdgcn_mfma_f32_16x16x32_bf16(af[m], buf_[n], accu[m][n], 0, 0, 0);
      }
    wait_vmcnt0();
    hard_barrier();
    cur ^= 1;
  }

#pragma unroll
  for (int m = 0; m < 4; m++) {
    const int rb = rowBase + wr * 64 + m * 16 + fq * 4;
#pragma unroll
    for (int n = 0; n < 4; n++) {
      const int col = colBase + wc * 64 + n * 16 + fr;
#pragma unroll
      for (int j = 0; j < 4; j++) {
        const int r = rb + j;
        if constexpr (GATHER) {
          if (r >= rowEnd) continue;
        }
        const float g = accg[m][n][j];
        const float u = accu[m][n][j];
        float v = g / (1.f + __expf(-g)) * u;
        if constexpr (GATHER) v *= slot_w[r];
        C[(size_t)r * N + col] = f2bf(v);
      }
    }
  }
}

// ---------------- down-projection GEMM: C = A * B^T (2-phase double-buffered) ----------------
// EXPERT=0: plain, write fp32 C. EXPERT=1: per-expert B, slot rows, write bf16.
template <int EXPERT>
__global__ __launch_bounds__(256) void down_gemm_k(const unsigned short* __restrict__ A,
                                                   const unsigned short* __restrict__ B,
                                                   void* __restrict__ Cp, int M, int N, int K,
                                                   const int* __restrict__ offs) {
  __shared__ __align__(16) unsigned short As[2][4096];
  __shared__ __align__(16) unsigned short Bs[2][4096];
  const int tid = threadIdx.x;
  const int lane = tid & 63;
  const int wid = tid >> 6;
  const int wr = wid >> 1, wc = wid & 1;
  const int fr = lane & 15, fq = lane >> 4;

  int rowBase, rowEnd;
  const unsigned short* Bp = B;
  if constexpr (EXPERT) {
    const int e = blockIdx.z;
    const int o0 = offs[e], o1 = offs[e + 1];
    rowBase = o0 + blockIdx.x * 128;
    if (rowBase >= o1) return;
    rowEnd = o1;
    Bp += (size_t)e * (size_t)N * (size_t)K;
  } else {
    rowBase = blockIdx.x * 128;
    rowEnd = M;
  }
  const int colBase = blockIdx.y * 128;

  const int rA = tid >> 2;
  const int kOff = (tid & 3) * 8;
  const int maxRow = (EXPERT ? NSLOTS : M) - 1;
  const int r0 = min(rowBase + rA, maxRow);
  const int r1 = min(rowBase + rA + 64, maxRow);
  const unsigned short* aRow0 = A + (size_t)r0 * (size_t)K;
  const unsigned short* aRow1 = A + (size_t)r1 * (size_t)K;
  const unsigned short* bRow0 = Bp + (size_t)(colBase + rA) * (size_t)K;
  const unsigned short* bRow1 = Bp + (size_t)(colBase + rA + 64) * (size_t)K;

  f32x4 acc[4][4];
#pragma unroll
  for (int i = 0; i < 4; i++)
#pragma unroll
    for (int j = 0; j < 4; j++) acc[i][j] = (f32x4){0.f, 0.f, 0.f, 0.f};

  const int ldOff = tid * 8;
  auto stage = [&](int b, int k0) {
    gload16(aRow0 + k0 + kOff, &As[b][ldOff]);
    gload16(aRow1 + k0 + kOff, &As[b][2048 + ldOff]);
    gload16(bRow0 + k0 + kOff, &Bs[b][ldOff]);
    gload16(bRow1 + k0 + kOff, &Bs[b][2048 + ldOff]);
  };

  const int rdA = (wr * 64 + fr) * 32 + fq * 8;
  const int rdB = (wc * 64 + fr) * 32 + fq * 8;

  const int nsteps = K >> 5;
  int cur = 0;
  stage(0, 0);
  wait_vmcnt0();
  hard_barrier();

  for (int s = 0; s < nsteps; ++s) {
    if (s + 1 < nsteps) stage(cur ^ 1, (s + 1) << 5);
    bf16x8 af[4], bfr[4];
#pragma unroll
    for (int m = 0; m < 4; m++) af[m] = *(const bf16x8*)(&As[cur][rdA + m * 512]);
#pragma unroll
    for (int n = 0; n < 4; n++) bfr[n] = *(const bf16x8*)(&Bs[cur][rdB + n * 512]);
    wait_lgkmcnt0();
    __builtin_amdgcn_sched_barrier(0);
#pragma unroll
    for (int m = 0; m < 4; m++)
#pragma unroll
      for (int n = 0; n < 4; n++)
        acc[m][n] = __builtin_amdgcn_mfma_f32_16x16x32_bf16(af[m], bfr[n], acc[m][n], 0, 0, 0);
    wait_vmcnt0();
    hard_barrier();
    cur ^= 1;
  }

#pragma unroll
  for (int m = 0; m < 4; m++) {
    const int rb = rowBase + wr * 64 + m * 16 + fq * 4;
#pragma unroll
    for (int n = 0; n < 4; n++) {
      const int col = colBase + wc * 64 + n * 16 + fr;
#pragma unroll
      for (int j = 0; j < 4; j++) {
        const int r = rb + j;
        if constexpr (EXPERT) {
          if (r >= rowEnd) continue;
          ((unsigned short*)Cp)[(size_t)r * N + col] = f2bf(acc[m][n][j]);
        } else {
          ((float*)Cp)[(size_t)r * N + col] = acc[m][n][j];
        }
      }
    }
  }
}

// ---------------- final combine: out[t] += dslot[s0[t]] + dslot[s1[t]] ----------------
__global__ void combine_kernel(float* __restrict__ out, const unsigned short* __restrict__ dslot,
                               const int* __restrict__ slot_pos) {
  const int t = blockIdx.x;
  const int s0 = slot_pos[t * 2 + 0];
  const int s1 = slot_pos[t * 2 + 1];
  const int c = threadIdx.x * 4;
  const ushort4 a = *(const ushort4*)(dslot + (size_t)s0 * HIDDEN + c);
  const ushort4 b = *(const ushort4*)(dslot + (size_t)s1 * HIDDEN + c);
  float4* o = (float4*)(out + (size_t)t * HIDDEN + c);
  float4 v = *o;
  v.x += bf2f(a.x) + bf2f(b.x);
  v.y += bf2f(a.y) + bf2f(b.y);
  v.z += bf2f(a.z) + bf2f(b.z);
  v.w += bf2f(a.w) + bf2f(b.w);
  *o = v;
}

// ---------------- workspace layout (bytes) ----------------
#define WS_XB 0ull                 // 4096*1024*2   = 8388608
#define WS_WEG 8388608ull          // 16*512*1024*2 = 16777216
#define WS_WEU 25165824ull         // 16777216
#define WS_WED 41943040ull         // 16*1024*512*2 = 16777216
#define WS_WSG 58720256ull         // 2048*1024*2   = 4194304
#define WS_WSU 62914560ull         // 4194304
#define WS_WSD 67108864ull         // 4194304
#define WS_INTERB 71303168ull      // 4096*2048*2   = 16777216
#define WS_INTERS 88080384ull      // 8192*512*2    = 8388608
#define WS_DSLOT 96468992ull       // 8192*1024*2   = 16777216
#define WS_SLOT_TOKEN 113246208ull // 8192*4
#define WS_SLOT_W 113278976ull     // 8192*4
#define WS_SLOT_POS 113311744ull   // 8192*4
#define WS_TOPK_IDX 113344512ull   // 8192*4
#define WS_TOPK_W 113377280ull     // 8192*4
#define WS_COUNTS 113410048ull     // 64
#define WS_OFFS 113410112ull       // 128
#define WS_CURSORS 113410240ull    // 64
#define WS_NEEDED 113410304ull

extern "C" void kernel_launch(void* const* d_in, const int* in_sizes, int n_in,
                              void* d_out, int out_size, void* d_ws, size_t ws_size,
                              hipStream_t stream) {
  if (ws_size < WS_NEEDED) return;

  const float* x = (const float*)d_in[0];
  const float* router_w = (const float*)d_in[1];
  const float* eg = (const float*)d_in[2];
  const float* eu = (const float*)d_in[3];
  const float* ed = (const float*)d_in[4];
  const float* sg = (const float*)d_in[5];
  const float* su = (const float*)d_in[6];
  const float* sd = (const float*)d_in[7];

  char* ws = (char*)d_ws;
  unsigned short* xb = (unsigned short*)(ws + WS_XB);
  unsigned short* weg = (unsigned short*)(ws + WS_WEG);
  unsigned short* weu = (unsigned short*)(ws + WS_WEU);
  unsigned short* wed = (unsigned short*)(ws + WS_WED);
  unsigned short* wsg = (unsigned short*)(ws + WS_WSG);
  unsigned short* wsu = (unsigned short*)(ws + WS_WSU);
  unsigned short* wsd = (unsigned short*)(ws + WS_WSD);
  unsigned short* interb = (unsigned short*)(ws + WS_INTERB);
  unsigned short* inters = (unsigned short*)(ws + WS_INTERS);
  unsigned short* dslot = (unsigned short*)(ws + WS_DSLOT);
  int* slot_token = (int*)(ws + WS_SLOT_TOKEN);
  float* slot_w = (float*)(ws + WS_SLOT_W);
  int* slot_pos = (int*)(ws + WS_SLOT_POS);
  int* topk_idx = (int*)(ws + WS_TOPK_IDX);
  float* topk_w = (float*)(ws + WS_TOPK_W);
  int* counts = (int*)(ws + WS_COUNTS);
  int* offs = (int*)(ws + WS_OFFS);
  int* cursors = (int*)(ws + WS_CURSORS);

  float* out = (float*)d_out;

  // --- routing (fp32, selection-exact) ---
  hipMemsetAsync(counts, 0, NEXP * sizeof(int), stream);
  router_kernel<<<TOKENS, 64, 0, stream>>>(x, router_w, topk_idx, topk_w, counts);
  offsets_kernel<<<1, 64, 0, stream>>>(counts, offs, cursors);
  build_slots_kernel<<<16, 256, 0, stream>>>(topk_idx, topk_w, offs, cursors,
                                             slot_token, slot_w, slot_pos);

  // --- bf16 conversions (weights transposed to [N,K]) ---
  convert_kernel<<<4096, 256, 0, stream>>>(x, xb, TOKENS * HIDDEN);
  transpose_convert_kernel<<<dim3(32, 16, 16), 256, 0, stream>>>(eg, weg, 1024, 512);
  transpose_convert_kernel<<<dim3(32, 16, 16), 256, 0, stream>>>(eu, weu, 1024, 512);
  transpose_convert_kernel<<<dim3(16, 32, 16), 256, 0, stream>>>(ed, wed, 512, 1024);
  transpose_convert_kernel<<<dim3(32, 64, 1), 256, 0, stream>>>(sg, wsg, 1024, 2048);
  transpose_convert_kernel<<<dim3(32, 64, 1), 256, 0, stream>>>(su, wsu, 1024, 2048);
  transpose_convert_kernel<<<dim3(64, 32, 1), 256, 0, stream>>>(sd, wsd, 2048, 1024);

  // --- shared expert: fused gate+up+silu -> down (writes all of d_out, fp32) ---
  fused_gu_k<0><<<dim3(32, 16, 1), 256, 0, stream>>>(xb, wsg, wsu, interb, TOKENS, DFF_S, HIDDEN,
                                                     nullptr, nullptr, nullptr);
  down_gemm_k<0><<<dim3(32, 8, 1), 256, 0, stream>>>(interb, wsd, out, TOKENS, HIDDEN, DFF_S, nullptr);

  // --- routed experts: fused gathered gate+up+silu*w -> per-slot down -> combine ---
  fused_gu_k<1><<<dim3(16, 4, 16), 256, 0, stream>>>(xb, weg, weu, inters, NSLOTS, DFF_E, HIDDEN,
                                                     offs, slot_token, slot_w);
  down_gemm_k<1><<<dim3(16, 8, 16), 256, 0, stream>>>(inters, wed, dslot, NSLOTS, HIDDEN, DFF_E, offs);
  combine_kernel<<<TOKENS, 256, 0, stream>>>(out, dslot, slot_pos);
}